// Round 13
// baseline (1254.940 us; speedup 1.0000x reference)
//
#include <hip/hip_runtime.h>
#include <hip/hip_bf16.h>
#include <math.h>

// Problem constants
#define TT   128
#define BB   256
#define DIN  256
#define DH   1024
#define DOUT 256

// R11-proven core (754us): H exchanged in MFMA B-fragment order (coalesced),
// flagless epoch-bit sync (each 8B word carries code(t)=1+((t-1)%15) in its 4
// halfword LSBs, written atomically by one AGST; consumers validate + AGLD
// retry), parity double buffer, AGLD/AGST agent-scope only.
//
// R13: halve the exchange traffic. NC=64 cols/block (4 col-tiles per wave
// sharing ONE 32KB B-read -> dup factor 32->16 -> 8 MB/step), W1h fragments
// in 128KB DYNAMIC LDS (gfx950: 160KB/CU; opt-in via hipFuncSetAttribute,
// checked synchronously on host). W1x fragments move to registers. Fallback:
// R11-exact kernel (same Hbuf layout, shared readout) if the opt-in fails.
// R12's version ring removed (it forced L2-miss fills from cold MALL/HBM:
// FETCH 72->106MB, 754->979us regression).
#define NGM 8

typedef float  floatx4 __attribute__((ext_vector_type(4)));
typedef short  shortx8 __attribute__((ext_vector_type(8)));
typedef unsigned long long u64;

#define CMASK 0x0001000100010001ULL
#define GSTRIDE 32768           // shorts per group slab (2*32*4*16*8)

__device__ __forceinline__ short f2bf(float f) {
    union { float f; unsigned u; } v; v.f = f;
    unsigned r = v.u + 0x7fffu + ((v.u >> 16) & 1u);   // RNE, inputs never NaN
    return (short)(r >> 16);
}

// RNE to the bf16 grid restricted to LSB==bit (step 2 ulp): err <= 1 ulp bf16
__device__ __forceinline__ unsigned short bf15e(float v, unsigned bit) {
    union { float f; unsigned u; } x; x.f = v;
    unsigned ua = x.u - (bit << 16);
    unsigned k  = (ua + 0xFFFFu + ((ua >> 17) & 1u)) >> 17;
    return (unsigned short)((k << 1) | bit);
}

__device__ __forceinline__ shortx8 mk8(u64 lo, u64 hi) {
    union { struct { u64 a, b; } s; shortx8 v; } u;
    u.s.a = lo; u.s.b = hi;
    return u.v;
}

__device__ __forceinline__ float fast_tanh(float z) {
    float e = __expf(2.0f * fabsf(z));
    float r = 1.0f - 2.0f / (e + 1.0f);
    return copysignf(r, z);
}

#define AGLD(p)    __hip_atomic_load((p),  __ATOMIC_RELAXED, __HIP_MEMORY_SCOPE_AGENT)
#define AGST(p, v) __hip_atomic_store((p), (v), __ATOMIC_RELAXED, __HIP_MEMORY_SCOPE_AGENT)

// coalesced AGLD chunk (8 ks-frags = 16 u64); hfr = slab + rt*16384+q*128+lr*8
#define LD16(buf, base) do { \
    _Pragma("unroll") \
    for (int _j = 0; _j < 8; ++_j) { \
        const u64* _p = (const u64*)(hfr + ((base) + _j) * 512); \
        buf[2 * _j]     = AGLD(_p); \
        buf[2 * _j + 1] = AGLD(_p + 1); \
    } } while (0)
#define OK16(buf, okvar) do { \
    int _o = 1; \
    _Pragma("unroll") \
    for (int _j = 0; _j < 16; ++_j) _o &= ((buf[_j] & CMASK) == pat); \
    okvar = __all(_o); } while (0)
#define WAITVALID(buf, base) do { \
    int _okk; OK16(buf, _okk); \
    while (!_okk) { __builtin_amdgcn_s_sleep(1); LD16(buf, base); OK16(buf, _okk); } \
    } while (0)

// ============================ NC=64 kernel ============================
// grid (8,16), 128 thr. Wave w = row-tile; 4 col-tiles (64 cols) per wave.
__global__ __launch_bounds__(128, 1) void rnn_steps_kernel64(
    const float* __restrict__ xs, const float* __restrict__ W1x,
    const float* __restrict__ W1h, const float* __restrict__ b1,
    short* __restrict__ Hbuf)
{
    const int gm  = blockIdx.x;   // 0..7 row group
    const int gn  = blockIdx.y;   // 0..15 col block (64 cols)
    const int tid = threadIdx.x;
    const int w   = tid >> 6;     // row-tile
    const int l   = tid & 63;
    const int lr  = l & 15;
    const int q   = l >> 4;

    const int r0 = gm * 32;
    const int c0 = gn * 64;

    // W1h A-fragments, dynamic LDS: frag index ((ks*4+ct)*4+qq), 16 lanes x 8
    extern __shared__ short WhL[];          // 32*4*4*16*8 shorts = 128 KB
    for (int idx = tid; idx < 8192; idx += 128) {
        const int c  = idx & 15;
        const int qq = (idx >> 4) & 3;
        const int ct = (idx >> 6) & 3;
        const int ks = idx >> 8;
        shortx8 f;
        #pragma unroll
        for (int j = 0; j < 8; ++j)
            f[j] = f2bf(W1h[(size_t)(ks * 32 + qq * 8 + j) * DH + c0 + ct * 16 + c]);
        *(shortx8*)&WhL[(size_t)(((ks * 4 + ct) * 4 + qq) * 16 + c) * 8] = f;
    }
    // W1x A-fragments register-resident: 4 ct x 8 ks = 128 VGPRs
    shortx8 wx[4][8];
    #pragma unroll
    for (int ct = 0; ct < 4; ++ct)
        #pragma unroll
        for (int ks = 0; ks < 8; ++ks) {
            shortx8 f;
            #pragma unroll
            for (int j = 0; j < 8; ++j)
                f[j] = f2bf(W1x[(size_t)(ks * 32 + q * 8 + j) * DH + c0 + ct * 16 + lr]);
            wx[ct][ks] = f;
        }
    __syncthreads();   // WhL ready; no barriers after this point

    floatx4 bias[4];
    #pragma unroll
    for (int ct = 0; ct < 4; ++ct)
        #pragma unroll
        for (int r = 0; r < 4; ++r) bias[ct][r] = b1[c0 + ct * 16 + q * 4 + r];

    const int myrow = r0 + w * 16 + lr;
    const size_t HS = (size_t)BB * DH;
    short* const Hg = Hbuf + gm * GSTRIDE;
    const int rdoff = w * 16384 + q * 128 + lr * 8;
    // store offsets per ct: col = gn*64+ct*16+q*4+r -> ks=2gn+(ct>>1),
    // qq=(ct&1)*2+(q>>1), j0=(q&1)*4
    int wroff[4];
    #pragma unroll
    for (int ct = 0; ct < 4; ++ct)
        wroff[ct] = w * 16384 + (gn * 2 + (ct >> 1)) * 512 +
                    ((ct & 1) * 2 + (q >> 1)) * 128 + lr * 8 + (q & 1) * 4;

    for (int t = 1; t <= TT; ++t) {
        const short* const hfr = Hg + (size_t)((t - 1) & 1) * HS + rdoff;
        const int pc = (t >= 2) ? (1 + ((t - 2) % 15)) : 0;
        const u64 pat = ((u64)(pc & 1)) | ((u64)((pc >> 1) & 1) << 16) |
                        ((u64)((pc >> 2) & 1) << 32) | ((u64)((pc >> 3) & 1) << 48);

        u64 A[16], B[16];
        if (t > 1) LD16(A, 0);   // early prefetch, self-correcting

        floatx4 acc[4] = {{0,0,0,0},{0,0,0,0},{0,0,0,0},{0,0,0,0}};

        // ---- x_t @ W1x: one B-frag feeds 4 MFMAs ----
        {
            const float* xrow = xs + ((size_t)(t - 1) * BB + myrow) * DIN + q * 8;
            #pragma unroll
            for (int ks = 0; ks < 8; ++ks) {
                floatx4 x0 = *(const floatx4*)(xrow + ks * 32);
                floatx4 x1 = *(const floatx4*)(xrow + ks * 32 + 4);
                shortx8 b;
                b[0] = f2bf(x0[0]); b[1] = f2bf(x0[1]); b[2] = f2bf(x0[2]); b[3] = f2bf(x0[3]);
                b[4] = f2bf(x1[0]); b[5] = f2bf(x1[1]); b[6] = f2bf(x1[2]); b[7] = f2bf(x1[3]);
                #pragma unroll
                for (int ct = 0; ct < 4; ++ct)
                    acc[ct] = __builtin_amdgcn_mfma_f32_16x16x32_bf16(wx[ct][ks], b, acc[ct], 0, 0, 0);
            }
        }

        // ---- h_{t-1} @ W1h: each loaded frag feeds 4 MFMAs ----
        if (t > 1) {
            #define CONS16_4(buf, base) do { \
                _Pragma("unroll") \
                for (int _j = 0; _j < 8; ++_j) { \
                    shortx8 bfr = mk8(buf[2 * _j], buf[2 * _j + 1]); \
                    _Pragma("unroll") \
                    for (int _ct = 0; _ct < 4; ++_ct) { \
                        const shortx8 a = *(const shortx8*)&WhL[ \
                            (size_t)(((((base) + _j) * 4 + _ct) * 4 + q) * 16 + lr) * 8]; \
                        acc[_ct] = __builtin_amdgcn_mfma_f32_16x16x32_bf16(a, bfr, acc[_ct], 0, 0, 0); \
                    } \
                } } while (0)
            LD16(B, 8);
            WAITVALID(A, 0);  CONS16_4(A, 0);
            LD16(A, 16);
            WAITVALID(B, 8);  CONS16_4(B, 8);
            LD16(B, 24);
            WAITVALID(A, 16); CONS16_4(A, 16);
            WAITVALID(B, 24); CONS16_4(B, 24);
            #undef CONS16_4
        }

        // ---- tanh, encode epoch bits, four 8B coalesced AGSTs ----
        {
            const int cc = 1 + ((t - 1) % 15);
            short* hv = Hg + (size_t)(t & 1) * HS;
            #pragma unroll
            for (int ct = 0; ct < 4; ++ct) {
                u64 p = 0;
                #pragma unroll
                for (int r = 0; r < 4; ++r) {
                    const unsigned bit = ((unsigned)cc >> r) & 1u;
                    p |= ((u64)bf15e(fast_tanh(acc[ct][r] + bias[ct][r]), bit)) << (16 * r);
                }
                AGST((u64*)(hv + wroff[ct]), p);
            }
        }
    }
}

// ============================ R11 fallback (NC=32) ============================
__global__ __launch_bounds__(128, 1) void rnn_steps_kernel32(
    const float* __restrict__ xs, const float* __restrict__ W1x,
    const float* __restrict__ W1h, const float* __restrict__ b1,
    short* __restrict__ Hbuf)
{
    const int gm  = blockIdx.x;
    const int gn  = blockIdx.y;
    const int tid = threadIdx.x;
    const int w   = tid >> 6;
    const int l   = tid & 63;
    const int lr  = l & 15;
    const int q   = l >> 4;

    const int r0 = gm * 32;
    const int c0 = gn * 32;

    __shared__ short WhL[DH / 32][2][4][16][8];   // 64 KB
    for (int idx = tid; idx < (DH / 32) * 2 * 4 * 16; idx += 128) {
        const int c  = idx & 15;
        const int qq = (idx >> 4) & 3;
        const int ct = (idx >> 6) & 1;
        const int ks = idx >> 7;
        shortx8 f;
        #pragma unroll
        for (int j = 0; j < 8; ++j)
            f[j] = f2bf(W1h[(size_t)(ks * 32 + qq * 8 + j) * DH + c0 + ct * 16 + c]);
        *(shortx8*)&WhL[ks][ct][qq][c][0] = f;
    }
    shortx8 wx[2][8];
    #pragma unroll
    for (int ct = 0; ct < 2; ++ct)
        #pragma unroll
        for (int ks = 0; ks < 8; ++ks) {
            shortx8 f;
            #pragma unroll
            for (int j = 0; j < 8; ++j)
                f[j] = f2bf(W1x[(size_t)(ks * 32 + q * 8 + j) * DH + c0 + ct * 16 + lr]);
            wx[ct][ks] = f;
        }
    __syncthreads();

    floatx4 bias[2];
    #pragma unroll
    for (int ct = 0; ct < 2; ++ct)
        #pragma unroll
        for (int r = 0; r < 4; ++r) bias[ct][r] = b1[c0 + ct * 16 + q * 4 + r];

    const int myrow = r0 + w * 16 + lr;
    const size_t HS = (size_t)BB * DH;
    short* const Hg = Hbuf + gm * GSTRIDE;
    const int rdoff = w * 16384 + q * 128 + lr * 8;
    const int wroff = w * 16384 + gn * 512 + (q >> 1) * 128 + lr * 8 + (q & 1) * 4;

    for (int t = 1; t <= TT; ++t) {
        const short* const hfr = Hg + (size_t)((t - 1) & 1) * HS + rdoff;
        const int pc = (t >= 2) ? (1 + ((t - 2) % 15)) : 0;
        const u64 pat = ((u64)(pc & 1)) | ((u64)((pc >> 1) & 1) << 16) |
                        ((u64)((pc >> 2) & 1) << 32) | ((u64)((pc >> 3) & 1) << 48);

        u64 A[16], B[16];
        if (t > 1) LD16(A, 0);

        floatx4 acc0 = {0.f, 0.f, 0.f, 0.f}, acc1 = {0.f, 0.f, 0.f, 0.f};
        {
            const float* xrow = xs + ((size_t)(t - 1) * BB + myrow) * DIN + q * 8;
            #pragma unroll
            for (int ks = 0; ks < 8; ++ks) {
                floatx4 x0 = *(const floatx4*)(xrow + ks * 32);
                floatx4 x1 = *(const floatx4*)(xrow + ks * 32 + 4);
                shortx8 b;
                b[0] = f2bf(x0[0]); b[1] = f2bf(x0[1]); b[2] = f2bf(x0[2]); b[3] = f2bf(x0[3]);
                b[4] = f2bf(x1[0]); b[5] = f2bf(x1[1]); b[6] = f2bf(x1[2]); b[7] = f2bf(x1[3]);
                acc0 = __builtin_amdgcn_mfma_f32_16x16x32_bf16(wx[0][ks], b, acc0, 0, 0, 0);
                acc1 = __builtin_amdgcn_mfma_f32_16x16x32_bf16(wx[1][ks], b, acc1, 0, 0, 0);
            }
        }
        if (t > 1) {
            #define CONS16_2(buf, base) do { \
                _Pragma("unroll") \
                for (int _j = 0; _j < 8; ++_j) { \
                    shortx8 bfr = mk8(buf[2 * _j], buf[2 * _j + 1]); \
                    shortx8 a0 = *(const shortx8*)&WhL[(base) + _j][0][q][lr][0]; \
                    shortx8 a1 = *(const shortx8*)&WhL[(base) + _j][1][q][lr][0]; \
                    acc0 = __builtin_amdgcn_mfma_f32_16x16x32_bf16(a0, bfr, acc0, 0, 0, 0); \
                    acc1 = __builtin_amdgcn_mfma_f32_16x16x32_bf16(a1, bfr, acc1, 0, 0, 0); \
                } } while (0)
            LD16(B, 8);
            WAITVALID(A, 0);  CONS16_2(A, 0);
            LD16(A, 16);
            WAITVALID(B, 8);  CONS16_2(B, 8);
            LD16(B, 24);
            WAITVALID(A, 16); CONS16_2(A, 16);
            WAITVALID(B, 24); CONS16_2(B, 24);
            #undef CONS16_2
        }
        {
            const int cc = 1 + ((t - 1) % 15);
            short* hp = Hg + (size_t)(t & 1) * HS + wroff;
            u64 p0 = 0, p1 = 0;
            #pragma unroll
            for (int r = 0; r < 4; ++r) {
                const unsigned bit = ((unsigned)cc >> r) & 1u;
                p0 |= ((u64)bf15e(fast_tanh(acc0[r] + bias[0][r]), bit)) << (16 * r);
                p1 |= ((u64)bf15e(fast_tanh(acc1[r] + bias[1][r]), bit)) << (16 * r);
            }
            AGST((u64*)(hp), p0);
            AGST((u64*)(hp + 256), p1);
        }
    }
}

// out[b][o] = sum_k h[b][k]*W2[k][o] + b2 ; final h (parity 0) in frag layout
__global__ __launch_bounds__(256) void readout_kernel(
    const short* __restrict__ Hfin, const float* __restrict__ W2,
    const float* __restrict__ b2, float* __restrict__ out)
{
    const int o  = threadIdx.x;
    const int b0 = blockIdx.x * 4;
    __shared__ u64 hs8[4 * DH / 4];
    for (int ch = o; ch < 4 * DH / 4; ch += 256) {
        const int row  = ch >> 8;
        const int col0 = (ch & 255) * 4;
        const int rr   = b0 + row;
        const int gmr  = rr >> 5, rt = (rr >> 4) & 1, lrr = rr & 15;
        const int ks   = col0 >> 5, qq = (col0 >> 3) & 3, j0 = col0 & 7;
        const u64* src = (const u64*)(Hfin + (size_t)gmr * GSTRIDE + rt * 16384 +
                                      ks * 512 + qq * 128 + lrr * 8 + j0);
        hs8[ch] = AGLD(src);
    }
    __syncthreads();
    const unsigned* h0 = (const unsigned*)&hs8[0 * 256];
    const unsigned* h1 = (const unsigned*)&hs8[1 * 256];
    const unsigned* h2 = (const unsigned*)&hs8[2 * 256];
    const unsigned* h3 = (const unsigned*)&hs8[3 * 256];
    float a0 = 0.f, a1 = 0.f, a2 = 0.f, a3 = 0.f;
    for (int k2 = 0; k2 < DH / 2; ++k2) {
        float w0 = W2[(2 * k2)     * DOUT + o];
        float w1 = W2[(2 * k2 + 1) * DOUT + o];
        unsigned p0 = h0[k2], p1 = h1[k2], p2 = h2[k2], p3 = h3[k2];
        a0 += __builtin_bit_cast(float, p0 << 16) * w0 + __builtin_bit_cast(float, p0 & 0xffff0000u) * w1;
        a1 += __builtin_bit_cast(float, p1 << 16) * w0 + __builtin_bit_cast(float, p1 & 0xffff0000u) * w1;
        a2 += __builtin_bit_cast(float, p2 << 16) * w0 + __builtin_bit_cast(float, p2 & 0xffff0000u) * w1;
        a3 += __builtin_bit_cast(float, p3 << 16) * w0 + __builtin_bit_cast(float, p3 & 0xffff0000u) * w1;
    }
    const float bias = b2[0];
    out[(b0 + 0) * DOUT + o] = a0 + bias;
    out[(b0 + 1) * DOUT + o] = a1 + bias;
    out[(b0 + 2) * DOUT + o] = a2 + bias;
    out[(b0 + 3) * DOUT + o] = a3 + bias;
}

extern "C" void kernel_launch(void* const* d_in, const int* in_sizes, int n_in,
                              void* d_out, int out_size, void* d_ws, size_t ws_size,
                              hipStream_t stream) {
    (void)in_sizes; (void)n_in; (void)out_size; (void)ws_size;
    const float* xs  = (const float*)d_in[0];
    const float* W1x = (const float*)d_in[1];
    const float* W1h = (const float*)d_in[2];
    const float* b1  = (const float*)d_in[3];
    const float* W2  = (const float*)d_in[4];
    const float* b2  = (const float*)d_in[5];
    float* out = (float*)d_out;

    // ws: parity double buffer (1 MB), fragment layout. No flags, no memset.
    short* Hbuf = (short*)d_ws;

    // Opt into 128KB dynamic LDS (synchronous host call, idempotent, same
    // every launch). Success -> NC=64 kernel; failure -> R11-exact fallback.
    hipError_t e = hipFuncSetAttribute(
        reinterpret_cast<const void*>(rnn_steps_kernel64),
        hipFuncAttributeMaxDynamicSharedMemorySize, 131072);
    if (e == hipSuccess) {
        rnn_steps_kernel64<<<dim3(NGM, 16), 128, 131072, stream>>>(
            xs, W1x, W1h, b1, Hbuf);
    } else {
        rnn_steps_kernel32<<<dim3(NGM, 32), 128, 0, stream>>>(
            xs, W1x, W1h, b1, Hbuf);
    }
    // t=128 -> parity 0 holds h_128
    readout_kernel<<<dim3(BB / 4), 256, 0, stream>>>(Hbuf, W2, b2, out);
}